// Round 2
// baseline (1657.836 us; speedup 1.0000x reference)
//
#include <hip/hip_runtime.h>
#include <hip/hip_bf16.h>
#include <stdint.h>

#define BB 32
#define NN 1024
#define CC 1024
#define LL 16

typedef __attribute__((ext_vector_type(4))) float f32x4;
typedef __attribute__((ext_vector_type(8))) short short8;
typedef __attribute__((ext_vector_type(4))) unsigned short ushort4v;

__device__ __forceinline__ unsigned short f2bf(float f) {
  union { float f; unsigned u; } v; v.f = f;
  unsigned r = v.u + 0x7FFF + ((v.u >> 16) & 1);
  return (unsigned short)(r >> 16);
}
__device__ __forceinline__ float bf2f(unsigned short h) {
  union { unsigned u; float f; } v; v.u = ((unsigned)h) << 16; return v.f;
}

// ---------------- weight prep: transpose->bf16 ----------------
// z=0: WkqT[j][k] = (j<512? keyW[k][j] : queryW[k][j-512])
// z=1: f1WT[j][k]=f1W[k][j]; z=2: f2WT; z=3: kWT; z=4: qWbf copy (no transpose)
__global__ __launch_bounds__(256) void wprep(
    const float* __restrict__ keyW, const float* __restrict__ queryW,
    const float* __restrict__ f1W, const float* __restrict__ f2W,
    const float* __restrict__ kW, const float* __restrict__ qW,
    unsigned short* __restrict__ WkqT, unsigned short* __restrict__ f1WT,
    unsigned short* __restrict__ f2WT, unsigned short* __restrict__ kWT,
    unsigned short* __restrict__ qWbf)
{
  int z = blockIdx.z;
  int tx = threadIdx.x, ty = threadIdx.y;
  if (z == 4) {
#pragma unroll
    for (int i = 0; i < 4; ++i) {
      int row = blockIdx.y * 32 + ty + 8 * i;
      int col = blockIdx.x * 32 + tx;
      qWbf[row * 1024 + col] = f2bf(qW[row * 1024 + col]);
    }
    return;
  }
  __shared__ float tile[32][33];
  int j0 = blockIdx.x * 32, k0 = blockIdx.y * 32;
  const float* src = (z == 1) ? f1W : (z == 2) ? f2W : kW;
#pragma unroll
  for (int i = 0; i < 4; ++i) {
    int k = k0 + ty + 8 * i;
    int j = j0 + tx;
    float v;
    if (z == 0) v = (j < 512) ? keyW[k * 512 + j] : queryW[k * 512 + (j - 512)];
    else        v = src[k * 1024 + j];
    tile[ty + 8 * i][tx] = v;
  }
  __syncthreads();
  unsigned short* dst = (z == 0) ? WkqT : (z == 1) ? f1WT : (z == 2) ? f2WT : kWT;
#pragma unroll
  for (int i = 0; i < 4; ++i) {
    int j = j0 + ty + 8 * i;
    dst[j * 1024 + k0 + tx] = f2bf(tile[tx][ty + 8 * i]);
  }
}

__global__ void bias_pack(const float* __restrict__ keyb,
                          const float* __restrict__ queryb,
                          float* __restrict__ biaskq) {
  int i = blockIdx.x * 256 + threadIdx.x;
  biaskq[i] = (i < 512) ? keyb[i] : queryb[i - 512];
}

// ---------------- tokenizer: proj^T[b][l][n] = X@tokW + tokb ----------------
__global__ __launch_bounds__(256) void proj_kernel(
    const float* __restrict__ X, const float* __restrict__ tokW,
    const float* __restrict__ tokB, float* __restrict__ projT)
{
  __shared__ float Ws[16][1024];   // tokW transposed [l][c]
  int tid = threadIdx.x;
#pragma unroll
  for (int i = 0; i < 16; ++i) {
    int fi = tid + 256 * i;        // f4 index over 4096
    int c = fi >> 2, l4 = (fi & 3) << 2;
    f32x4 g = *(const f32x4*)&tokW[c * 16 + l4];
    Ws[l4 + 0][c] = g[0]; Ws[l4 + 1][c] = g[1];
    Ws[l4 + 2][c] = g[2]; Ws[l4 + 3][c] = g[3];
  }
  __syncthreads();
  int b = blockIdx.y;
  int wv = tid >> 6, lane = tid & 63, p = lane >> 4, j = lane & 15;
  float tb = tokB[j];
  for (int g = 0; g < 4; ++g) {
    int pix = blockIdx.x * 64 + wv * 16 + g * 4 + p;
    const float* xr = X + ((size_t)b * NN + pix) * CC;
    float acc[16];
#pragma unroll
    for (int l = 0; l < 16; ++l) acc[l] = 0.f;
#pragma unroll
    for (int k = 0; k < 16; ++k) {
      int c = j * 4 + k * 64;
      f32x4 xv = *(const f32x4*)&xr[c];
#pragma unroll
      for (int l = 0; l < 16; ++l) {
        f32x4 w4 = *(const f32x4*)&Ws[l][c];
        acc[l] += xv[0]*w4[0] + xv[1]*w4[1] + xv[2]*w4[2] + xv[3]*w4[3];
      }
    }
#pragma unroll
    for (int l = 0; l < 16; ++l) {
      float v = acc[l];
      v += __shfl_xor(v, 1); v += __shfl_xor(v, 2);
      v += __shfl_xor(v, 4); v += __shfl_xor(v, 8);
      acc[l] = v;
    }
    float out = acc[0];
#pragma unroll
    for (int l = 1; l < 16; ++l) out = (j == l) ? acc[l] : out;
    projT[((size_t)b * LL + j) * NN + pix] = out + tb;
  }
}

// ---------------- softmax over N (rows of projT) ----------------
__global__ __launch_bounds__(256) void softmax_n(float* __restrict__ projT) {
  float* row = projT + (size_t)blockIdx.x * NN;
  int t = threadIdx.x;
  f32x4 v = ((f32x4*)row)[t];
  float m = fmaxf(fmaxf(v[0], v[1]), fmaxf(v[2], v[3]));
#pragma unroll
  for (int msk = 32; msk >= 1; msk >>= 1) m = fmaxf(m, __shfl_xor(m, msk));
  __shared__ float redm[4], reds[4];
  if ((t & 63) == 0) redm[t >> 6] = m;
  __syncthreads();
  m = fmaxf(fmaxf(redm[0], redm[1]), fmaxf(redm[2], redm[3]));
  f32x4 e;
  e[0] = __expf(v[0] - m); e[1] = __expf(v[1] - m);
  e[2] = __expf(v[2] - m); e[3] = __expf(v[3] - m);
  float s = e[0] + e[1] + e[2] + e[3];
#pragma unroll
  for (int msk = 32; msk >= 1; msk >>= 1) s += __shfl_xor(s, msk);
  if ((t & 63) == 0) reds[t >> 6] = s;
  __syncthreads();
  s = reds[0] + reds[1] + reds[2] + reds[3];
  float inv = 1.f / s;
  e[0] *= inv; e[1] *= inv; e[2] *= inv; e[3] *= inv;
  ((f32x4*)row)[t] = e;
}

// ---------------- T partial: Tpart[b][ch][l][c] = sum_n attn[l][n]*X[n][c] ----------------
__global__ __launch_bounds__(256) void tpart_kernel(
    const float* __restrict__ X, const float* __restrict__ attnT,
    float* __restrict__ Tpart)
{
  int b = blockIdx.y, ch = blockIdx.x;   // ch<8, 128 pixels each
  int n0 = ch * 128;
  __shared__ float att[128][16];
  int tid = threadIdx.x;
#pragma unroll
  for (int i = 0; i < 2; ++i) {
    int fi = tid + 256 * i;              // f4 over 512
    int l = fi >> 5, n4 = (fi & 31) << 2;
    f32x4 a = *(const f32x4*)&attnT[((size_t)b * LL + l) * NN + n0 + n4];
    att[n4 + 0][l] = a[0]; att[n4 + 1][l] = a[1];
    att[n4 + 2][l] = a[2]; att[n4 + 3][l] = a[3];
  }
  __syncthreads();
  int c4 = tid * 4;
  f32x4 acc[16];
#pragma unroll
  for (int l = 0; l < 16; ++l) acc[l] = (f32x4)0.f;
  const float* xp = X + ((size_t)b * NN + n0) * CC + c4;
#pragma unroll 4
  for (int n = 0; n < 128; ++n) {
    f32x4 xv = *(const f32x4*)(xp + (size_t)n * CC);
    const f32x4* arow = (const f32x4*)&att[n][0];
    f32x4 a0 = arow[0], a1 = arow[1], a2 = arow[2], a3 = arow[3];
    acc[0]  += a0[0]*xv; acc[1]  += a0[1]*xv; acc[2]  += a0[2]*xv; acc[3]  += a0[3]*xv;
    acc[4]  += a1[0]*xv; acc[5]  += a1[1]*xv; acc[6]  += a1[2]*xv; acc[7]  += a1[3]*xv;
    acc[8]  += a2[0]*xv; acc[9]  += a2[1]*xv; acc[10] += a2[2]*xv; acc[11] += a2[3]*xv;
    acc[12] += a3[0]*xv; acc[13] += a3[1]*xv; acc[14] += a3[2]*xv; acc[15] += a3[3]*xv;
  }
  float* out = Tpart + (((size_t)b * 8 + ch) * LL) * CC + c4;
#pragma unroll
  for (int l = 0; l < 16; ++l)
    *(f32x4*)(out + (size_t)l * CC) = acc[l];
}

__global__ void treduce(const float* __restrict__ Tpart, float* __restrict__ T,
                        unsigned short* __restrict__ Tbf) {
  int f = blockIdx.x * 256 + threadIdx.x;   // f4 index < 131072
  int b = f >> 12, w = f & 4095;
  const f32x4* src = (const f32x4*)Tpart;
  f32x4 s = (f32x4)0.f;
#pragma unroll
  for (int ch = 0; ch < 8; ++ch) s += src[((size_t)(b * 8 + ch)) * 4096 + w];
  ((f32x4*)T)[f] = s;
  ushort4v h; h[0]=f2bf(s[0]); h[1]=f2bf(s[1]); h[2]=f2bf(s[2]); h[3]=f2bf(s[3]);
  ((ushort4v*)Tbf)[f] = h;
}

// ---------------- generic NT bf16 MFMA GEMM (K=1024) ----------------
// A [M,K] bf16 row-major, Bm [Nn,K] bf16 row-major. out = A@Bm^T (+bias,relu,res)
template<int RELU, int HAS_BIAS, int HAS_RES, int STORE_F32, int STORE_BF16>
__global__ __launch_bounds__(256) void gemm_nt(
    const unsigned short* __restrict__ A, const unsigned short* __restrict__ Bm,
    const float* __restrict__ bias, const float* __restrict__ res,
    float* __restrict__ outF, unsigned short* __restrict__ outB,
    int M, int Nn)
{
  const int K = 1024;
  __shared__ unsigned short As[64 * 32], Bs[64 * 32];
  int tid = threadIdx.x;
  int wid = tid >> 6, lane = tid & 63;
  int m0 = blockIdx.x * 64, n0 = blockIdx.y * 64;
  int wm = (wid >> 1) * 32, wn = (wid & 1) * 32;
  f32x4 acc00 = (f32x4)0.f, acc01 = (f32x4)0.f, acc10 = (f32x4)0.f, acc11 = (f32x4)0.f;
  int srow = tid >> 2, scol = (tid & 3) << 3;
  const unsigned short* Ag = A + (size_t)(m0 + srow) * K + scol;
  const unsigned short* Bg = Bm + (size_t)(n0 + srow) * K + scol;
  int lr = lane & 15, kg = (lane >> 4) << 3;
  const unsigned short* a0p = &As[(wm + lr) * 32 + kg];
  const unsigned short* a1p = &As[(wm + 16 + lr) * 32 + kg];
  const unsigned short* b0p = &Bs[(wn + lr) * 32 + kg];
  const unsigned short* b1p = &Bs[(wn + 16 + lr) * 32 + kg];
  for (int k0 = 0; k0 < K; k0 += 32) {
    short8 av = *(const short8*)(Ag + k0);
    short8 bv = *(const short8*)(Bg + k0);
    *(short8*)&As[tid * 8] = av;
    *(short8*)&Bs[tid * 8] = bv;
    __syncthreads();
    short8 a0 = *(const short8*)a0p, a1 = *(const short8*)a1p;
    short8 b0 = *(const short8*)b0p, b1 = *(const short8*)b1p;
    acc00 = __builtin_amdgcn_mfma_f32_16x16x32_bf16(a0, b0, acc00, 0, 0, 0);
    acc01 = __builtin_amdgcn_mfma_f32_16x16x32_bf16(a0, b1, acc01, 0, 0, 0);
    acc10 = __builtin_amdgcn_mfma_f32_16x16x32_bf16(a1, b0, acc10, 0, 0, 0);
    acc11 = __builtin_amdgcn_mfma_f32_16x16x32_bf16(a1, b1, acc11, 0, 0, 0);
    __syncthreads();
  }
  int rbase = (lane >> 4) << 2;
  f32x4 accs[2][2] = {{acc00, acc01}, {acc10, acc11}};
#pragma unroll
  for (int sm = 0; sm < 2; ++sm) {
#pragma unroll
    for (int sn = 0; sn < 2; ++sn) {
      int row0 = m0 + wm + sm * 16 + rbase;
      int col  = n0 + wn + sn * 16 + lr;
      float bv_ = HAS_BIAS ? bias[col] : 0.f;
      f32x4 v = accs[sm][sn];
#pragma unroll
      for (int rr = 0; rr < 4; ++rr) {
        float x = v[rr] + bv_;
        if (RELU) x = fmaxf(x, 0.f);
        size_t idx = (size_t)(row0 + rr) * Nn + col;
        if (HAS_RES) x += res[idx];
        if (STORE_F32) outF[idx] = x;
        if (STORE_BF16) outB[idx] = f2bf(x);
      }
    }
  }
}

// ---------------- token self-attention: scores+softmax+T_dash ----------------
__global__ __launch_bounds__(256) void scores_tdash(
    const float* __restrict__ kq, const float* __restrict__ T,
    float* __restrict__ Tdash, unsigned short* __restrict__ Tdbf)
{
  int b = blockIdx.x;
  __shared__ float Ts[16][1024];
  int tid = threadIdx.x;
#pragma unroll
  for (int i = 0; i < 16; ++i) {
    int fi = tid + 256 * i;
    int rrow = fi >> 8, c4 = (fi & 255) << 2;
    *(f32x4*)&Ts[rrow][c4] = *(const f32x4*)&T[((size_t)b * LL + rrow) * CC + c4];
  }
  __syncthreads();
  int l = tid >> 4, mcol = tid & 15, lane = tid & 63;
  const float* krow = kq + ((size_t)b * LL + l) * CC;          // cols 0..511 = k
  const float* qrow = kq + ((size_t)b * LL + mcol) * CC + 512; // cols 512..1023 = q
  float s = 0.f;
#pragma unroll 8
  for (int d = 0; d < 512; d += 4) {
    f32x4 kv = *(const f32x4*)(krow + d);
    f32x4 qv = *(const f32x4*)(qrow + d);
    s += kv[0]*qv[0] + kv[1]*qv[1] + kv[2]*qv[2] + kv[3]*qv[3];
  }
  float mx = s;
  mx = fmaxf(mx, __shfl_xor(mx, 1)); mx = fmaxf(mx, __shfl_xor(mx, 2));
  mx = fmaxf(mx, __shfl_xor(mx, 4)); mx = fmaxf(mx, __shfl_xor(mx, 8));
  float e = __expf(s - mx);
  float sum = e;
  sum += __shfl_xor(sum, 1); sum += __shfl_xor(sum, 2);
  sum += __shfl_xor(sum, 4); sum += __shfl_xor(sum, 8);
  float pv = e / sum;
  float pl[16];
#pragma unroll
  for (int i = 0; i < 16; ++i) pl[i] = __shfl(pv, (lane & 48) + i);
  float* od = Tdash + ((size_t)b * LL + l) * CC;
  unsigned short* ob = Tdbf + ((size_t)b * LL + l) * CC;
#pragma unroll
  for (int i = 0; i < 16; ++i) {
    int c = mcol * 4 + i * 64;
    f32x4 o = *(const f32x4*)&Ts[l][c];
#pragma unroll
    for (int m = 0; m < 16; ++m) {
      f32x4 tv = *(const f32x4*)&Ts[m][c];
      o += pl[m] * tv;
    }
    *(f32x4*)(od + c) = o;
    ushort4v h; h[0]=f2bf(o[0]); h[1]=f2bf(o[1]); h[2]=f2bf(o[2]); h[3]=f2bf(o[3]);
    *(ushort4v*)(ob + c) = h;
  }
}

// ---------------- r[b,l] = q_b . Tk[b,l,:] ----------------
__global__ __launch_bounds__(256) void r_kernel(
    const unsigned short* __restrict__ Tkbf, const float* __restrict__ qb,
    float* __restrict__ r)
{
  int row = blockIdx.x * 4 + (threadIdx.x >> 6);
  int lane = threadIdx.x & 63;
  const unsigned short* p = Tkbf + (size_t)row * CC;
  float s = 0.f;
#pragma unroll
  for (int h = 0; h < 2; ++h) {
    int d0 = lane * 8 + h * 512;
    short8 v = *(const short8*)&p[d0];
#pragma unroll
    for (int jj = 0; jj < 8; ++jj)
      s += bf2f((unsigned short)v[jj]) * qb[d0 + jj];
  }
#pragma unroll
  for (int msk = 32; msk >= 1; msk >>= 1) s += __shfl_xor(s, msk);
  if (lane == 0) r[row] = s;
}

// ---------------- sim + softmax over L -> P ----------------
__global__ __launch_bounds__(256) void sim_kernel(
    const float* __restrict__ X, const float* __restrict__ G,
    const float* __restrict__ r, float* __restrict__ P)
{
  __shared__ float Gs[16][1024];   // [l][c]
  int b = blockIdx.y, tid = threadIdx.x;
#pragma unroll
  for (int i = 0; i < 16; ++i) {
    int fi = tid + 256 * i;
    int c = fi >> 2, l4 = (fi & 3) << 2;
    f32x4 gval = *(const f32x4*)&G[(size_t)c * 512 + b * 16 + l4];
    Gs[l4+0][c] = gval[0]; Gs[l4+1][c] = gval[1];
    Gs[l4+2][c] = gval[2]; Gs[l4+3][c] = gval[3];
  }
  __syncthreads();
  int wv = tid >> 6, lane = tid & 63, p = lane >> 4, j = lane & 15;
  float rl[16];
#pragma unroll
  for (int i = 0; i < 4; ++i) {
    f32x4 rv = *(const f32x4*)&r[b * 16 + i * 4];
    rl[i*4+0]=rv[0]; rl[i*4+1]=rv[1]; rl[i*4+2]=rv[2]; rl[i*4+3]=rv[3];
  }
  for (int g = 0; g < 4; ++g) {
    int pix = blockIdx.x * 64 + wv * 16 + g * 4 + p;
    const float* xr = X + ((size_t)b * NN + pix) * CC;
    float acc[16];
#pragma unroll
    for (int l = 0; l < 16; ++l) acc[l] = 0.f;
#pragma unroll
    for (int k = 0; k < 16; ++k) {
      int c = j * 4 + k * 64;
      f32x4 xv = *(const f32x4*)&xr[c];
#pragma unroll
      for (int l = 0; l < 16; ++l) {
        f32x4 gv = *(const f32x4*)&Gs[l][c];
        acc[l] += xv[0]*gv[0] + xv[1]*gv[1] + xv[2]*gv[2] + xv[3]*gv[3];
      }
    }
#pragma unroll
    for (int l = 0; l < 16; ++l) {
      float v = acc[l];
      v += __shfl_xor(v, 1); v += __shfl_xor(v, 2);
      v += __shfl_xor(v, 4); v += __shfl_xor(v, 8);
      acc[l] = v + rl[l];
    }
    float mx = acc[0];
#pragma unroll
    for (int l = 1; l < 16; ++l) mx = fmaxf(mx, acc[l]);
    float sum = 0.f; float ex[16];
#pragma unroll
    for (int l = 0; l < 16; ++l) { ex[l] = __expf(acc[l] - mx); sum += ex[l]; }
    float inv = 1.f / sum;
    float out = ex[0];
#pragma unroll
    for (int l = 1; l < 16; ++l) out = (j == l) ? ex[l] : out;
    P[((size_t)b * NN + pix) * LL + j] = out * inv;
  }
}

// ---------------- X_out = X + P @ T_out ----------------
__global__ __launch_bounds__(256) void out_kernel(
    const float* __restrict__ X, const float* __restrict__ P,
    const float* __restrict__ Tout, float* __restrict__ Xout)
{
  __shared__ float Ts[16][1024];
  int b = blockIdx.y, tid = threadIdx.x;
#pragma unroll
  for (int i = 0; i < 16; ++i) {
    int fi = tid + 256 * i;
    int rrow = fi >> 8, c4 = (fi & 255) << 2;
    *(f32x4*)&Ts[rrow][c4] = *(const f32x4*)&Tout[((size_t)b * LL + rrow) * CC + c4];
  }
  __syncthreads();
  int wv = tid >> 6, lane = tid & 63, p = lane >> 4, j = lane & 15;
  for (int g = 0; g < 4; ++g) {
    int pix = blockIdx.x * 64 + wv * 16 + g * 4 + p;
    const float* xr = X + ((size_t)b * NN + pix) * CC;
    float* orow = Xout + ((size_t)b * NN + pix) * CC;
    const float* pr = P + ((size_t)b * NN + pix) * LL;
    float pl[16];
#pragma unroll
    for (int i = 0; i < 4; ++i) {
      f32x4 pvv = *(const f32x4*)&pr[i * 4];
      pl[i*4+0]=pvv[0]; pl[i*4+1]=pvv[1]; pl[i*4+2]=pvv[2]; pl[i*4+3]=pvv[3];
    }
#pragma unroll
    for (int k = 0; k < 16; ++k) {
      int c = j * 4 + k * 64;
      f32x4 o = *(const f32x4*)&xr[c];
#pragma unroll
      for (int l = 0; l < 16; ++l) {
        f32x4 tv = *(const f32x4*)&Ts[l][c];
        o += pl[l] * tv;
      }
      *(f32x4*)&orow[c] = o;
    }
  }
}

extern "C" void kernel_launch(void* const* d_in, const int* in_sizes, int n_in,
                              void* d_out, int out_size, void* d_ws, size_t ws_size,
                              hipStream_t stream)
{
  const float* X      = (const float*)d_in[0];
  const float* tokW   = (const float*)d_in[2];
  const float* tokB   = (const float*)d_in[3];
  const float* keyW   = (const float*)d_in[4];
  const float* keyB   = (const float*)d_in[5];
  const float* queryW = (const float*)d_in[6];
  const float* queryB = (const float*)d_in[7];
  const float* f1W    = (const float*)d_in[8];
  const float* f1B    = (const float*)d_in[9];
  const float* f2W    = (const float*)d_in[10];
  const float* f2B    = (const float*)d_in[11];
  const float* qW     = (const float*)d_in[12];
  const float* qB     = (const float*)d_in[13];
  const float* kW     = (const float*)d_in[14];
  const float* kB     = (const float*)d_in[15];

  float* Xout = (float*)d_out;
  float* Tout = (float*)d_out + (size_t)BB * NN * CC;

  char* ws = (char*)d_ws;
  size_t off = 0;
  auto alloc_f = [&](size_t n) { float* pp = (float*)(ws + off); off += n * 4; return pp; };
  float* attn   = alloc_f(524288);    // [B][L][N]  (proj^T, softmaxed in place)
  float* Tbuf   = alloc_f(524288);    // [B][L][C]
  float* kqbuf  = alloc_f(524288);    // [B*L][1024]  (k | q)
  float* Tdash  = alloc_f(524288);
  float* Gbuf   = alloc_f(524288);    // [C][B*L]
  float* Pbuf   = alloc_f(524288);    // [B][N][L]
  float* rbuf   = alloc_f(512);
  float* biaskq = alloc_f(1024);
  float* Tpart  = alloc_f(4194304);   // [B][8][L][C]
  auto alloc_h = [&](size_t n) { unsigned short* pp = (unsigned short*)(ws + off); off += n * 2; return pp; };
  unsigned short* Tbf    = alloc_h(524288);
  unsigned short* Tdbf   = alloc_h(524288);
  unsigned short* Hbf    = alloc_h(524288);
  unsigned short* Toutbf = alloc_h(524288);
  unsigned short* Tkbf   = alloc_h(524288);
  unsigned short* WkqT   = alloc_h(1048576);
  unsigned short* f1WT   = alloc_h(1048576);
  unsigned short* f2WT   = alloc_h(1048576);
  unsigned short* kWT    = alloc_h(1048576);
  unsigned short* qWbf   = alloc_h(1048576);
  (void)ws_size; (void)in_sizes; (void)n_in; (void)out_size;

  wprep<<<dim3(32, 32, 5), dim3(32, 8), 0, stream>>>(keyW, queryW, f1W, f2W, kW, qW,
                                                     WkqT, f1WT, f2WT, kWT, qWbf);
  bias_pack<<<4, 256, 0, stream>>>(keyB, queryB, biaskq);
  proj_kernel<<<dim3(16, 32), 256, 0, stream>>>(X, tokW, tokB, attn);
  softmax_n<<<512, 256, 0, stream>>>(attn);
  tpart_kernel<<<dim3(8, 32), 256, 0, stream>>>(X, attn, Tpart);
  treduce<<<512, 256, 0, stream>>>(Tpart, Tbuf, Tbf);
  gemm_nt<0,1,0,1,0><<<dim3(8, 16), 256, 0, stream>>>(Tbf, WkqT, biaskq, nullptr, kqbuf, nullptr, 512, 1024);
  scores_tdash<<<32, 256, 0, stream>>>(kqbuf, Tbuf, Tdash, Tdbf);
  gemm_nt<1,1,0,0,1><<<dim3(8, 16), 256, 0, stream>>>(Tdbf, f1WT, f1B, nullptr, nullptr, Hbf, 512, 1024);
  gemm_nt<0,1,1,1,1><<<dim3(8, 16), 256, 0, stream>>>(Hbf, f2WT, f2B, Tdash, Tout, Toutbf, 512, 1024);
  gemm_nt<0,1,0,0,1><<<dim3(8, 16), 256, 0, stream>>>(Toutbf, kWT, kB, nullptr, nullptr, Tkbf, 512, 1024);
  r_kernel<<<128, 256, 0, stream>>>(Tkbf, qB, rbuf);
  gemm_nt<0,0,0,1,0><<<dim3(16, 8), 256, 0, stream>>>(qWbf, Tkbf, nullptr, nullptr, Gbuf, nullptr, 1024, 512);
  sim_kernel<<<dim3(16, 32), 256, 0, stream>>>(X, Gbuf, rbuf, Pbuf);
  out_kernel<<<dim3(16, 32), 256, 0, stream>>>(X, Pbuf, Tout, Xout);
}

// Round 3
// 211.852 us; speedup vs baseline: 7.8255x; 7.8255x over previous
//
#include <hip/hip_runtime.h>
#include <hip/hip_bf16.h>
#include <stdint.h>

#define BB 32
#define NN 1024
#define CC 1024
#define LL 16

typedef __attribute__((ext_vector_type(4))) float f32x4;
typedef __attribute__((ext_vector_type(8))) short short8;
typedef __attribute__((ext_vector_type(4))) unsigned short ushort4v;

__device__ __forceinline__ unsigned short f2bf(float f) {
  union { float f; unsigned u; } v; v.f = f;
  unsigned r = v.u + 0x7FFF + ((v.u >> 16) & 1);
  return (unsigned short)(r >> 16);
}
__device__ __forceinline__ float bf2f(unsigned short h) {
  union { unsigned u; float f; } v; v.u = ((unsigned)h) << 16; return v.f;
}

// ---------------- weight prep: transpose->bf16 ----------------
__global__ __launch_bounds__(256) void wprep(
    const float* __restrict__ keyW, const float* __restrict__ queryW,
    const float* __restrict__ f1W, const float* __restrict__ f2W,
    const float* __restrict__ kW, const float* __restrict__ qW,
    unsigned short* __restrict__ WkqT, unsigned short* __restrict__ f1WT,
    unsigned short* __restrict__ f2WT, unsigned short* __restrict__ kWT,
    unsigned short* __restrict__ qWbf)
{
  int z = blockIdx.z;
  int tx = threadIdx.x, ty = threadIdx.y;
  if (z == 4) {
#pragma unroll
    for (int i = 0; i < 4; ++i) {
      int row = blockIdx.y * 32 + ty + 8 * i;
      int col = blockIdx.x * 32 + tx;
      qWbf[row * 1024 + col] = f2bf(qW[row * 1024 + col]);
    }
    return;
  }
  __shared__ float tile[32][33];
  int j0 = blockIdx.x * 32, k0 = blockIdx.y * 32;
  const float* src = (z == 1) ? f1W : (z == 2) ? f2W : kW;
#pragma unroll
  for (int i = 0; i < 4; ++i) {
    int k = k0 + ty + 8 * i;
    int j = j0 + tx;
    float v;
    if (z == 0) v = (j < 512) ? keyW[k * 512 + j] : queryW[k * 512 + (j - 512)];
    else        v = src[k * 1024 + j];
    tile[ty + 8 * i][tx] = v;
  }
  __syncthreads();
  unsigned short* dst = (z == 0) ? WkqT : (z == 1) ? f1WT : (z == 2) ? f2WT : kWT;
#pragma unroll
  for (int i = 0; i < 4; ++i) {
    int j = j0 + ty + 8 * i;
    dst[j * 1024 + k0 + tx] = f2bf(tile[tx][ty + 8 * i]);
  }
}

// tokWT[l][c] = bf16(tokW[c][l])
__global__ void tokprep(const float* __restrict__ tokW, unsigned short* __restrict__ tokWT) {
  int i = blockIdx.x * 256 + threadIdx.x;   // 16384
  int l = i >> 10, c = i & 1023;
  tokWT[i] = f2bf(tokW[c * 16 + l]);
}

__global__ void bias_pack(const float* __restrict__ keyb,
                          const float* __restrict__ queryb,
                          float* __restrict__ biaskq) {
  int i = blockIdx.x * 256 + threadIdx.x;
  biaskq[i] = (i < 512) ? keyb[i] : queryb[i - 512];
}

// ---------------- pixel-stream MFMA: out = X @ Wt^T (+bias) ----------------
// Wt is [16][1024] bf16 (proj: tokWT, same all batches) or [B*16][1024] (sim: Gt).
// IS_SIM=0: write logits transposed to out[(b*16+l)*1024 + n].
// IS_SIM=1: in-register softmax over l, write P to out[pix*16 + l].
template<int IS_SIM>
__global__ __launch_bounds__(256) void pix_mfma(
    const float* __restrict__ X, const unsigned short* __restrict__ Wt,
    const float* __restrict__ bias, float* __restrict__ out)
{
  __shared__ __align__(16) char sp[16384];   // 64 rows x 128 c bf16, XOR-swizzled
  int tid = threadIdx.x, wid = tid >> 6, lane = tid & 63;
  int lr = lane & 15, hi = lane >> 4;
  int pix0 = blockIdx.x * 64 + blockIdx.y * 1024;
  int b = pix0 >> 10;
  int row = tid >> 2, seg = tid & 3;
  const float* xr = X + (size_t)(pix0 + row) * 1024 + seg * 32;
  const unsigned short* Wb = Wt + (IS_SIM ? ((size_t)b * 16 * 1024) : (size_t)0)
                             + (size_t)lr * 1024 + hi * 8;
  int wbyte[4];
#pragma unroll
  for (int u = 0; u < 4; ++u)
    wbyte[u] = row * 256 + (((seg * 64 + u * 16) ^ ((row & 7) << 4)));
  int arow = wid * 16 + lr;
  int rbyte = arow * 256;
  int rx = (arow & 7) << 4;
  f32x4 acc = (f32x4)0.f;
  for (int k0 = 0; k0 < 1024; k0 += 128) {
    f32x4 v[8];
#pragma unroll
    for (int i = 0; i < 8; ++i) v[i] = *(const f32x4*)(xr + k0 + i * 4);
    __syncthreads();
#pragma unroll
    for (int u = 0; u < 4; ++u) {
      short8 pk;
      pk[0] = (short)f2bf(v[2*u][0]);   pk[1] = (short)f2bf(v[2*u][1]);
      pk[2] = (short)f2bf(v[2*u][2]);   pk[3] = (short)f2bf(v[2*u][3]);
      pk[4] = (short)f2bf(v[2*u+1][0]); pk[5] = (short)f2bf(v[2*u+1][1]);
      pk[6] = (short)f2bf(v[2*u+1][2]); pk[7] = (short)f2bf(v[2*u+1][3]);
      *(short8*)(sp + wbyte[u]) = pk;
    }
    __syncthreads();
#pragma unroll
    for (int kk = 0; kk < 4; ++kk) {
      short8 af = *(const short8*)(sp + rbyte + (((kk * 64 + hi * 16) ^ rx)));
      short8 bf = *(const short8*)(Wb + k0 + kk * 32);
      acc = __builtin_amdgcn_mfma_f32_16x16x32_bf16(af, bf, acc, 0, 0, 0);
    }
  }
  int pixb = pix0 + wid * 16 + hi * 4;
  if (!IS_SIM) {
    float bv = bias[lr];
#pragma unroll
    for (int rr = 0; rr < 4; ++rr) {
      int pix = pixb + rr;
      out[((size_t)b * 16 + lr) * 1024 + (pix & 1023)] = acc[rr] + bv;
    }
  } else {
    float bv = bias[b * 16 + lr];
#pragma unroll
    for (int rr = 0; rr < 4; ++rr) {
      float vv = acc[rr] + bv;
      float mx = vv;
      mx = fmaxf(mx, __shfl_xor(mx, 1)); mx = fmaxf(mx, __shfl_xor(mx, 2));
      mx = fmaxf(mx, __shfl_xor(mx, 4)); mx = fmaxf(mx, __shfl_xor(mx, 8));
      float e = __expf(vv - mx);
      float ss = e;
      ss += __shfl_xor(ss, 1); ss += __shfl_xor(ss, 2);
      ss += __shfl_xor(ss, 4); ss += __shfl_xor(ss, 8);
      out[(size_t)(pixb + rr) * 16 + lr] = e / ss;
    }
  }
}

// ---------------- softmax over N (rows of attn [B*L][N]) ----------------
__global__ __launch_bounds__(256) void softmax_n(float* __restrict__ projT) {
  float* row = projT + (size_t)blockIdx.x * NN;
  int t = threadIdx.x;
  f32x4 v = ((f32x4*)row)[t];
  float m = fmaxf(fmaxf(v[0], v[1]), fmaxf(v[2], v[3]));
#pragma unroll
  for (int msk = 32; msk >= 1; msk >>= 1) m = fmaxf(m, __shfl_xor(m, msk));
  __shared__ float redm[4], reds[4];
  if ((t & 63) == 0) redm[t >> 6] = m;
  __syncthreads();
  m = fmaxf(fmaxf(redm[0], redm[1]), fmaxf(redm[2], redm[3]));
  f32x4 e;
  e[0] = __expf(v[0] - m); e[1] = __expf(v[1] - m);
  e[2] = __expf(v[2] - m); e[3] = __expf(v[3] - m);
  float s = e[0] + e[1] + e[2] + e[3];
#pragma unroll
  for (int msk = 32; msk >= 1; msk >>= 1) s += __shfl_xor(s, msk);
  if ((t & 63) == 0) reds[t >> 6] = s;
  __syncthreads();
  s = reds[0] + reds[1] + reds[2] + reds[3];
  float inv = 1.f / s;
  e[0] *= inv; e[1] *= inv; e[2] *= inv; e[3] *= inv;
  ((f32x4*)row)[t] = e;
}

// ---------------- T partials: bf16 [b][ch=16][l][c], chunk = 64 pixels ----------------
__global__ __launch_bounds__(256) void tpart_kernel(
    const float* __restrict__ X, const float* __restrict__ attnT,
    unsigned short* __restrict__ TpartBf)
{
  int b = blockIdx.y, ch = blockIdx.x;   // ch<16
  int n0 = ch * 64;
  __shared__ float att[64][16];
  int tid = threadIdx.x;
  {
    int l = tid >> 4, n4 = (tid & 15) * 4;
    f32x4 a = *(const f32x4*)&attnT[((size_t)b * 16 + l) * 1024 + n0 + n4];
    att[n4 + 0][l] = a[0]; att[n4 + 1][l] = a[1];
    att[n4 + 2][l] = a[2]; att[n4 + 3][l] = a[3];
  }
  __syncthreads();
  f32x4 acc[16];
#pragma unroll
  for (int l = 0; l < 16; ++l) acc[l] = (f32x4)0.f;
  const float* xp = X + ((size_t)b * 1024 + n0) * 1024 + tid * 4;
#pragma unroll 4
  for (int n = 0; n < 64; ++n) {
    f32x4 xv = *(const f32x4*)(xp + (size_t)n * 1024);
    const f32x4* ar = (const f32x4*)&att[n][0];
    f32x4 a0 = ar[0], a1 = ar[1], a2 = ar[2], a3 = ar[3];
    acc[0]  += a0[0]*xv; acc[1]  += a0[1]*xv; acc[2]  += a0[2]*xv; acc[3]  += a0[3]*xv;
    acc[4]  += a1[0]*xv; acc[5]  += a1[1]*xv; acc[6]  += a1[2]*xv; acc[7]  += a1[3]*xv;
    acc[8]  += a2[0]*xv; acc[9]  += a2[1]*xv; acc[10] += a2[2]*xv; acc[11] += a2[3]*xv;
    acc[12] += a3[0]*xv; acc[13] += a3[1]*xv; acc[14] += a3[2]*xv; acc[15] += a3[3]*xv;
  }
  unsigned short* op = TpartBf + (size_t)(b * 16 + ch) * 16 * 1024 + tid * 4;
#pragma unroll
  for (int l = 0; l < 16; ++l) {
    f32x4 s = acc[l];
    ushort4v h; h[0]=f2bf(s[0]); h[1]=f2bf(s[1]); h[2]=f2bf(s[2]); h[3]=f2bf(s[3]);
    *(ushort4v*)(op + (size_t)l * 1024) = h;
  }
}

__global__ void treduce(const unsigned short* __restrict__ TpartBf,
                        float* __restrict__ T, unsigned short* __restrict__ Tbf) {
  int f = blockIdx.x * 256 + threadIdx.x;   // f4 index < 131072
  int b = f >> 12, w = f & 4095;
  f32x4 s = (f32x4)0.f;
#pragma unroll
  for (int ch = 0; ch < 16; ++ch) {
    ushort4v h = ((const ushort4v*)TpartBf)[(size_t)(b * 16 + ch) * 4096 + w];
    s[0] += bf2f(h[0]); s[1] += bf2f(h[1]); s[2] += bf2f(h[2]); s[3] += bf2f(h[3]);
  }
  ((f32x4*)T)[f] = s;
  ushort4v h; h[0]=f2bf(s[0]); h[1]=f2bf(s[1]); h[2]=f2bf(s[2]); h[3]=f2bf(s[3]);
  ((ushort4v*)Tbf)[f] = h;
}

// ---------------- NT bf16 GEMM, M=512, Nn=1024, K=1024, 32x64 tiles ----------------
template<int RELU, int HAS_BIAS, int HAS_RES, int STORE_F32, int STORE_BF16>
__global__ __launch_bounds__(256) void gemm32x64(
    const unsigned short* __restrict__ A, const unsigned short* __restrict__ Bm,
    const float* __restrict__ bias, const float* __restrict__ res,
    float* __restrict__ outF, unsigned short* __restrict__ outB)
{
  const int K = 1024;
  __shared__ __align__(16) char sh[12288];   // As 4KB | Bs 8KB, XOR-swizzled rows of 128B
  char* Asp = sh;
  char* Bsp = sh + 4096;
  int tid = threadIdx.x, wid = tid >> 6, lane = tid & 63;
  int lr = lane & 15, hi = lane >> 4;
  int m0 = blockIdx.x * 32, n0 = blockIdx.y * 64;
  int arow = tid >> 3, acol = (tid & 7) * 8;   // A stage: 32x64
  int brow = tid >> 2, bcol = (tid & 3) * 16;  // B stage: 64x64
  const unsigned short* Ap = A + (size_t)(m0 + arow) * K + acol;
  const unsigned short* Bp = Bm + (size_t)(n0 + brow) * K + bcol;
  int aw  = arow * 128 + (((acol * 2) ^ ((arow & 7) << 4)));
  int bw0 = brow * 128 + (((bcol * 2) ^ ((brow & 7) << 4)));
  int bw1 = brow * 128 + ((((bcol * 2) + 16) ^ ((brow & 7) << 4)));
  short8 aR[2]; short8 bR[2][2];
  aR[0]    = *(const short8*)(Ap);
  bR[0][0] = *(const short8*)(Bp);
  bR[0][1] = *(const short8*)(Bp + 8);
  aR[1]    = *(const short8*)(Ap + 64);
  bR[1][0] = *(const short8*)(Bp + 64);
  bR[1][1] = *(const short8*)(Bp + 72);
  f32x4 acc[2];
  acc[0] = (f32x4)0.f; acc[1] = (f32x4)0.f;
  int wm = (wid >> 1) * 16, wn = (wid & 1) * 32;
  int arb = (wm + lr) * 128, arx = ((wm + lr) & 7) << 4;
  for (int s = 0; s < 16; ++s) {
    __syncthreads();
    *(short8*)(Asp + aw)  = aR[s & 1];
    *(short8*)(Bsp + bw0) = bR[s & 1][0];
    *(short8*)(Bsp + bw1) = bR[s & 1][1];
    __syncthreads();
    if (s + 2 < 16) {
      int k0 = (s + 2) * 64;
      aR[s & 1]    = *(const short8*)(Ap + k0);
      bR[s & 1][0] = *(const short8*)(Bp + k0);
      bR[s & 1][1] = *(const short8*)(Bp + k0 + 8);
    }
#pragma unroll
    for (int kk = 0; kk < 2; ++kk) {
      short8 af = *(const short8*)(Asp + arb + (((kk * 64 + hi * 16) ^ arx)));
#pragma unroll
      for (int sn = 0; sn < 2; ++sn) {
        int br = wn + sn * 16 + lr;
        short8 bf = *(const short8*)(Bsp + br * 128 + (((kk * 64 + hi * 16) ^ ((br & 7) << 4))));
        acc[sn] = __builtin_amdgcn_mfma_f32_16x16x32_bf16(af, bf, acc[sn], 0, 0, 0);
      }
    }
  }
  int row0 = m0 + wm + hi * 4;
#pragma unroll
  for (int sn = 0; sn < 2; ++sn) {
    int col = n0 + wn + sn * 16 + lr;
    float bv_ = HAS_BIAS ? bias[col] : 0.f;
#pragma unroll
    for (int rr = 0; rr < 4; ++rr) {
      float x = acc[sn][rr] + bv_;
      if (RELU) x = fmaxf(x, 0.f);
      size_t idx = (size_t)(row0 + rr) * 1024 + col;
      if (HAS_RES) x += res[idx];
      if (STORE_F32) outF[idx] = x;
      if (STORE_BF16) outB[idx] = f2bf(x);
    }
  }
}

// ---------------- token self-attn: scores + softmax + T_dash (c-split 8) ----------------
__global__ __launch_bounds__(256) void scores_tdash(
    const float* __restrict__ kq, const float* __restrict__ T,
    float* __restrict__ Tdash, unsigned short* __restrict__ Tdbf)
{
  int cs = blockIdx.x, b = blockIdx.y;
  int c0 = cs * 128;
  __shared__ float Ts[16][128];
  int tid = threadIdx.x, lane = tid & 63;
#pragma unroll
  for (int i = 0; i < 2; ++i) {
    int fi = tid + 256 * i;            // f4 over 512
    int rrow = fi >> 5, c4 = (fi & 31) * 4;
    *(f32x4*)&Ts[rrow][c4] = *(const f32x4*)&T[((size_t)b * 16 + rrow) * 1024 + c0 + c4];
  }
  __syncthreads();
  int l = tid >> 4, m = tid & 15;
  const float* krow = kq + ((size_t)b * 16 + l) * 1024;
  const float* qrow = kq + ((size_t)b * 16 + m) * 1024 + 512;
  float s = 0.f;
#pragma unroll 8
  for (int d = 0; d < 512; d += 4) {
    f32x4 kv = *(const f32x4*)(krow + d);
    f32x4 qv = *(const f32x4*)(qrow + d);
    s += kv[0]*qv[0] + kv[1]*qv[1] + kv[2]*qv[2] + kv[3]*qv[3];
  }
  float mx = s;
  mx = fmaxf(mx, __shfl_xor(mx, 1)); mx = fmaxf(mx, __shfl_xor(mx, 2));
  mx = fmaxf(mx, __shfl_xor(mx, 4)); mx = fmaxf(mx, __shfl_xor(mx, 8));
  float e = __expf(s - mx);
  float sum = e;
  sum += __shfl_xor(sum, 1); sum += __shfl_xor(sum, 2);
  sum += __shfl_xor(sum, 4); sum += __shfl_xor(sum, 8);
  float pv = e / sum;
  float pl[16];
#pragma unroll
  for (int i = 0; i < 16; ++i) pl[i] = __shfl(pv, (lane & 48) + i);
  float* od = Tdash + ((size_t)b * 16 + l) * 1024 + c0;
  unsigned short* ob = Tdbf + ((size_t)b * 16 + l) * 1024 + c0;
#pragma unroll
  for (int h = 0; h < 2; ++h) {
    int c = m * 8 + h * 4;
    f32x4 o = *(const f32x4*)&Ts[l][c];
#pragma unroll
    for (int mm = 0; mm < 16; ++mm) {
      f32x4 tv = *(const f32x4*)&Ts[mm][c];
      o += pl[mm] * tv;
    }
    *(f32x4*)(od + c) = o;
    ushort4v hh; hh[0]=f2bf(o[0]); hh[1]=f2bf(o[1]); hh[2]=f2bf(o[2]); hh[3]=f2bf(o[3]);
    *(ushort4v*)(ob + c) = hh;
  }
}

// ---------------- r[b,l] = q_b . Tk[b,l,:] ----------------
__global__ __launch_bounds__(256) void r_kernel(
    const unsigned short* __restrict__ Tkbf, const float* __restrict__ qb,
    float* __restrict__ r)
{
  int row = blockIdx.x * 4 + (threadIdx.x >> 6);
  int lane = threadIdx.x & 63;
  const unsigned short* p = Tkbf + (size_t)row * CC;
  float s = 0.f;
#pragma unroll
  for (int h = 0; h < 2; ++h) {
    int d0 = lane * 8 + h * 512;
    short8 v = *(const short8*)&p[d0];
#pragma unroll
    for (int jj = 0; jj < 8; ++jj)
      s += bf2f((unsigned short)v[jj]) * qb[d0 + jj];
  }
#pragma unroll
  for (int msk = 32; msk >= 1; msk >>= 1) s += __shfl_xor(s, msk);
  if (lane == 0) r[row] = s;
}

// ---------------- X_out = X + P @ T_out (T_out column-slice in registers) ----------------
__global__ __launch_bounds__(256) void out_kernel(
    const float* __restrict__ X, const float* __restrict__ P,
    const float* __restrict__ Tout, float* __restrict__ Xout)
{
  int b = blockIdx.y, ch = blockIdx.x;   // 16 chunks x 64 pixels
  int tid = threadIdx.x;
  int c4 = tid * 4;
  f32x4 tsr[16];
#pragma unroll
  for (int l = 0; l < 16; ++l)
    tsr[l] = *(const f32x4*)&Tout[((size_t)b * 16 + l) * 1024 + c4];
  __shared__ float Ps[64][16];
  {
    int px = tid >> 2, q = (tid & 3) * 4;
    *(f32x4*)&Ps[px][q] = *(const f32x4*)&P[(size_t)(b * 1024 + ch * 64 + px) * 16 + q];
  }
  __syncthreads();
  const float* xp = X + ((size_t)b * 1024 + ch * 64) * 1024 + c4;
  float* op = Xout + ((size_t)b * 1024 + ch * 64) * 1024 + c4;
#pragma unroll 2
  for (int n = 0; n < 64; ++n) {
    f32x4 xv = *(const f32x4*)(xp + (size_t)n * 1024);
    const f32x4* pr = (const f32x4*)&Ps[n][0];
    f32x4 p0 = pr[0], p1 = pr[1], p2 = pr[2], p3 = pr[3];
    f32x4 o = xv;
    o += p0[0]*tsr[0];  o += p0[1]*tsr[1];  o += p0[2]*tsr[2];  o += p0[3]*tsr[3];
    o += p1[0]*tsr[4];  o += p1[1]*tsr[5];  o += p1[2]*tsr[6];  o += p1[3]*tsr[7];
    o += p2[0]*tsr[8];  o += p2[1]*tsr[9];  o += p2[2]*tsr[10]; o += p2[3]*tsr[11];
    o += p3[0]*tsr[12]; o += p3[1]*tsr[13]; o += p3[2]*tsr[14]; o += p3[3]*tsr[15];
    *(f32x4*)(op + (size_t)n * 1024) = o;
  }
}

extern "C" void kernel_launch(void* const* d_in, const int* in_sizes, int n_in,
                              void* d_out, int out_size, void* d_ws, size_t ws_size,
                              hipStream_t stream)
{
  const float* X      = (const float*)d_in[0];
  const float* tokW   = (const float*)d_in[2];
  const float* tokB   = (const float*)d_in[3];
  const float* keyW   = (const float*)d_in[4];
  const float* keyB   = (const float*)d_in[5];
  const float* queryW = (const float*)d_in[6];
  const float* queryB = (const float*)d_in[7];
  const float* f1W    = (const float*)d_in[8];
  const float* f1B    = (const float*)d_in[9];
  const float* f2W    = (const float*)d_in[10];
  const float* f2B    = (const float*)d_in[11];
  const float* qW     = (const float*)d_in[12];
  const float* qB     = (const float*)d_in[13];
  const float* kW     = (const float*)d_in[14];
  const float* kB     = (const float*)d_in[15];

  float* Xout = (float*)d_out;
  float* Tout = (float*)d_out + (size_t)BB * NN * CC;

  char* ws = (char*)d_ws;
  size_t off = 0;
  auto alloc_f = [&](size_t n) { float* pp = (float*)(ws + off); off += n * 4; return pp; };
  float* attn   = alloc_f(524288);    // [B*L][N] logits -> softmaxed in place
  float* Tbuf   = alloc_f(524288);    // [B*L][C]
  float* kqbuf  = alloc_f(524288);    // [B*L][1024] (k | q)
  float* Tdash  = alloc_f(524288);
  float* Pbuf   = alloc_f(524288);    // [B*N][16]
  float* rbuf   = alloc_f(1024);
  float* biaskq = alloc_f(1024);
  auto alloc_h = [&](size_t n) { unsigned short* pp = (unsigned short*)(ws + off); off += n * 2; return pp; };
  unsigned short* TpartBf = alloc_h(8388608);   // [B][16][L][C] bf16
  unsigned short* Tbf    = alloc_h(524288);
  unsigned short* Tdbf   = alloc_h(524288);
  unsigned short* Hbf    = alloc_h(524288);
  unsigned short* Toutbf = alloc_h(524288);
  unsigned short* Tkbf   = alloc_h(524288);
  unsigned short* Gtbf   = alloc_h(524288);     // [B*L][C] bf16
  unsigned short* WkqT   = alloc_h(1048576);
  unsigned short* f1WT   = alloc_h(1048576);
  unsigned short* f2WT   = alloc_h(1048576);
  unsigned short* kWT    = alloc_h(1048576);
  unsigned short* qWbf   = alloc_h(1048576);
  unsigned short* tokWT  = alloc_h(16384);
  (void)ws_size; (void)in_sizes; (void)n_in; (void)out_size;

  wprep<<<dim3(32, 32, 5), dim3(32, 8), 0, stream>>>(keyW, queryW, f1W, f2W, kW, qW,
                                                     WkqT, f1WT, f2WT, kWT, qWbf);
  tokprep<<<64, 256, 0, stream>>>(tokW, tokWT);
  bias_pack<<<4, 256, 0, stream>>>(keyB, queryB, biaskq);
  pix_mfma<0><<<dim3(512, 1), 256, 0, stream>>>(X, tokWT, tokB, attn);
  softmax_n<<<512, 256, 0, stream>>>(attn);
  tpart_kernel<<<dim3(16, 32), 256, 0, stream>>>(X, attn, TpartBf);
  treduce<<<512, 256, 0, stream>>>(TpartBf, Tbuf, Tbf);
  gemm32x64<0,1,0,1,0><<<dim3(16, 16), 256, 0, stream>>>(Tbf, WkqT, biaskq, nullptr, kqbuf, nullptr);
  scores_tdash<<<dim3(8, 32), 256, 0, stream>>>(kqbuf, Tbuf, Tdash, Tdbf);
  gemm32x64<1,1,0,0,1><<<dim3(16, 16), 256, 0, stream>>>(Tdbf, f1WT, f1B, nullptr, nullptr, Hbf);
  gemm32x64<0,1,1,1,1><<<dim3(16, 16), 256, 0, stream>>>(Hbf, f2WT, f2B, Tdash, Tout, Toutbf);
  gemm32x64<0,1,0,0,1><<<dim3(16, 16), 256, 0, stream>>>(Toutbf, kWT, kB, nullptr, nullptr, Tkbf);
  r_kernel<<<128, 256, 0, stream>>>(Tkbf, qB, rbuf);
  gemm32x64<0,0,0,0,1><<<dim3(16, 16), 256, 0, stream>>>(Tkbf, qWbf, nullptr, nullptr, nullptr, Gtbf);
  pix_mfma<1><<<dim3(16, 32), 256, 0, stream>>>(X, Gtbf, rbuf, Pbuf);
  out_kernel<<<dim3(16, 32), 256, 0, stream>>>(X, Pbuf, Tout, Xout);
}

// Round 4
// 210.604 us; speedup vs baseline: 7.8718x; 1.0059x over previous
//
#include <hip/hip_runtime.h>
#include <hip/hip_bf16.h>
#include <stdint.h>

#define BB 32
#define NN 1024
#define CC 1024
#define LL 16

typedef __attribute__((ext_vector_type(4))) float f32x4;
typedef __attribute__((ext_vector_type(8))) short short8;
typedef __attribute__((ext_vector_type(4))) unsigned short ushort4v;

__device__ __forceinline__ unsigned short f2bf(float f) {
  union { float f; unsigned u; } v; v.f = f;
  unsigned r = v.u + 0x7FFF + ((v.u >> 16) & 1);
  return (unsigned short)(r >> 16);
}
__device__ __forceinline__ float bf2f(unsigned short h) {
  union { unsigned u; float f; } v; v.u = ((unsigned)h) << 16; return v.f;
}

// ---------------- weight prep: transpose->bf16 (+ tokW^T, bias pack at z=5) ----------------
__global__ __launch_bounds__(256) void wprep(
    const float* __restrict__ keyW, const float* __restrict__ queryW,
    const float* __restrict__ f1W, const float* __restrict__ f2W,
    const float* __restrict__ kW, const float* __restrict__ qW,
    const float* __restrict__ tokW, const float* __restrict__ keyb,
    const float* __restrict__ queryb,
    unsigned short* __restrict__ WkqT, unsigned short* __restrict__ f1WT,
    unsigned short* __restrict__ f2WT, unsigned short* __restrict__ kWT,
    unsigned short* __restrict__ qWbf, unsigned short* __restrict__ tokWT,
    float* __restrict__ biaskq)
{
  int z = blockIdx.z;
  int tx = threadIdx.x, ty = threadIdx.y;
  if (z == 5) {
    int gid = (blockIdx.y * 32 + blockIdx.x) * 256 + ty * 32 + tx;
    if (gid < 16384) {
      int l = gid >> 10, c = gid & 1023;
      tokWT[gid] = f2bf(tokW[c * 16 + l]);
    } else if (gid < 17408) {
      int i = gid - 16384;
      biaskq[i] = (i < 512) ? keyb[i] : queryb[i - 512];
    }
    return;
  }
  if (z == 4) {
#pragma unroll
    for (int i = 0; i < 4; ++i) {
      int row = blockIdx.y * 32 + ty + 8 * i;
      int col = blockIdx.x * 32 + tx;
      qWbf[row * 1024 + col] = f2bf(qW[row * 1024 + col]);
    }
    return;
  }
  __shared__ float tile[32][33];
  int j0 = blockIdx.x * 32, k0 = blockIdx.y * 32;
  const float* src = (z == 1) ? f1W : (z == 2) ? f2W : kW;
#pragma unroll
  for (int i = 0; i < 4; ++i) {
    int k = k0 + ty + 8 * i;
    int j = j0 + tx;
    float v;
    if (z == 0) v = (j < 512) ? keyW[k * 512 + j] : queryW[k * 512 + (j - 512)];
    else        v = src[k * 1024 + j];
    tile[ty + 8 * i][tx] = v;
  }
  __syncthreads();
  unsigned short* dst = (z == 0) ? WkqT : (z == 1) ? f1WT : (z == 2) ? f2WT : kWT;
#pragma unroll
  for (int i = 0; i < 4; ++i) {
    int j = j0 + ty + 8 * i;
    dst[j * 1024 + k0 + tx] = f2bf(tile[tx][ty + 8 * i]);
  }
}

// ---------------- proj: attn logits transposed, out[(b*16+l)*1024+n] ----------------
__global__ __launch_bounds__(256) void proj_mfma(
    const float* __restrict__ X, const unsigned short* __restrict__ Wt,
    const float* __restrict__ bias, float* __restrict__ out)
{
  __shared__ __align__(16) char sp[16384];   // 64 rows x 128 c bf16, XOR-swizzled
  int tid = threadIdx.x, wid = tid >> 6, lane = tid & 63;
  int lr = lane & 15, hi = lane >> 4;
  int pix0 = blockIdx.x * 64;
  int b = pix0 >> 10;
  int row = tid >> 2, seg = tid & 3;
  const float* xr = X + (size_t)(pix0 + row) * 1024 + seg * 32;
  const unsigned short* Wb = Wt + (size_t)lr * 1024 + hi * 8;
  int wbyte[4];
#pragma unroll
  for (int u = 0; u < 4; ++u)
    wbyte[u] = row * 256 + (((seg * 64 + u * 16) ^ ((row & 7) << 4)));
  int arow = wid * 16 + lr;
  int rbyte = arow * 256;
  int rx = (arow & 7) << 4;
  f32x4 acc = (f32x4)0.f;
  for (int k0 = 0; k0 < 1024; k0 += 128) {
    f32x4 v[8];
#pragma unroll
    for (int i = 0; i < 8; ++i) v[i] = *(const f32x4*)(xr + k0 + i * 4);
    __syncthreads();
#pragma unroll
    for (int u = 0; u < 4; ++u) {
      short8 pk;
      pk[0] = (short)f2bf(v[2*u][0]);   pk[1] = (short)f2bf(v[2*u][1]);
      pk[2] = (short)f2bf(v[2*u][2]);   pk[3] = (short)f2bf(v[2*u][3]);
      pk[4] = (short)f2bf(v[2*u+1][0]); pk[5] = (short)f2bf(v[2*u+1][1]);
      pk[6] = (short)f2bf(v[2*u+1][2]); pk[7] = (short)f2bf(v[2*u+1][3]);
      *(short8*)(sp + wbyte[u]) = pk;
    }
    __syncthreads();
#pragma unroll
    for (int kk = 0; kk < 4; ++kk) {
      short8 af = *(const short8*)(sp + rbyte + (((kk * 64 + hi * 16) ^ rx)));
      short8 bf = *(const short8*)(Wb + k0 + kk * 32);
      acc = __builtin_amdgcn_mfma_f32_16x16x32_bf16(af, bf, acc, 0, 0, 0);
    }
  }
  int pixb = pix0 + wid * 16 + hi * 4;
  float bv = bias[lr];
#pragma unroll
  for (int rr = 0; rr < 4; ++rr) {
    int pix = pixb + rr;
    out[((size_t)b * 16 + lr) * 1024 + (pix & 1023)] = acc[rr] + bv;
  }
}

// ---------------- softmax over N (rows of attn [B*L][N]) ----------------
__global__ __launch_bounds__(256) void softmax_n(float* __restrict__ projT) {
  float* row = projT + (size_t)blockIdx.x * NN;
  int t = threadIdx.x;
  f32x4 v = ((f32x4*)row)[t];
  float m = fmaxf(fmaxf(v[0], v[1]), fmaxf(v[2], v[3]));
#pragma unroll
  for (int msk = 32; msk >= 1; msk >>= 1) m = fmaxf(m, __shfl_xor(m, msk));
  __shared__ float redm[4], reds[4];
  if ((t & 63) == 0) redm[t >> 6] = m;
  __syncthreads();
  m = fmaxf(fmaxf(redm[0], redm[1]), fmaxf(redm[2], redm[3]));
  f32x4 e;
  e[0] = __expf(v[0] - m); e[1] = __expf(v[1] - m);
  e[2] = __expf(v[2] - m); e[3] = __expf(v[3] - m);
  float s = e[0] + e[1] + e[2] + e[3];
#pragma unroll
  for (int msk = 32; msk >= 1; msk >>= 1) s += __shfl_xor(s, msk);
  if ((t & 63) == 0) reds[t >> 6] = s;
  __syncthreads();
  s = reds[0] + reds[1] + reds[2] + reds[3];
  float inv = 1.f / s;
  e[0] *= inv; e[1] *= inv; e[2] *= inv; e[3] *= inv;
  ((f32x4*)row)[t] = e;
}

// ---------------- T partials: bf16 [b][ch=8][l][c], chunk = 128 pixels ----------------
__global__ __launch_bounds__(256) void tpart_kernel(
    const float* __restrict__ X, const float* __restrict__ attnT,
    unsigned short* __restrict__ TpartBf)
{
  int b = blockIdx.y, ch = blockIdx.x;   // ch<8
  int n0 = ch * 128;
  __shared__ float att[128][16];
  int tid = threadIdx.x;
#pragma unroll
  for (int i = 0; i < 2; ++i) {
    int fi = tid + 256 * i;              // f4 over 512
    int l = fi >> 5, n4 = (fi & 31) << 2;
    f32x4 a = *(const f32x4*)&attnT[((size_t)b * 16 + l) * 1024 + n0 + n4];
    att[n4 + 0][l] = a[0]; att[n4 + 1][l] = a[1];
    att[n4 + 2][l] = a[2]; att[n4 + 3][l] = a[3];
  }
  __syncthreads();
  f32x4 acc[16];
#pragma unroll
  for (int l = 0; l < 16; ++l) acc[l] = (f32x4)0.f;
  const float* xp = X + ((size_t)b * 1024 + n0) * 1024 + tid * 4;
#pragma unroll 4
  for (int n = 0; n < 128; ++n) {
    f32x4 xv = *(const f32x4*)(xp + (size_t)n * 1024);
    const f32x4* ar = (const f32x4*)&att[n][0];
    f32x4 a0 = ar[0], a1 = ar[1], a2 = ar[2], a3 = ar[3];
    acc[0]  += a0[0]*xv; acc[1]  += a0[1]*xv; acc[2]  += a0[2]*xv; acc[3]  += a0[3]*xv;
    acc[4]  += a1[0]*xv; acc[5]  += a1[1]*xv; acc[6]  += a1[2]*xv; acc[7]  += a1[3]*xv;
    acc[8]  += a2[0]*xv; acc[9]  += a2[1]*xv; acc[10] += a2[2]*xv; acc[11] += a2[3]*xv;
    acc[12] += a3[0]*xv; acc[13] += a3[1]*xv; acc[14] += a3[2]*xv; acc[15] += a3[3]*xv;
  }
  unsigned short* op = TpartBf + (size_t)(b * 8 + ch) * 16 * 1024 + tid * 4;
#pragma unroll
  for (int l = 0; l < 16; ++l) {
    f32x4 s = acc[l];
    ushort4v h; h[0]=f2bf(s[0]); h[1]=f2bf(s[1]); h[2]=f2bf(s[2]); h[3]=f2bf(s[3]);
    *(ushort4v*)(op + (size_t)l * 1024) = h;
  }
}

__global__ void treduce(const unsigned short* __restrict__ TpartBf,
                        float* __restrict__ T, unsigned short* __restrict__ Tbf) {
  int f = blockIdx.x * 256 + threadIdx.x;   // f4 index < 131072
  int b = f >> 12, w = f & 4095;
  f32x4 s = (f32x4)0.f;
#pragma unroll
  for (int ch = 0; ch < 8; ++ch) {
    ushort4v h = ((const ushort4v*)TpartBf)[(size_t)(b * 8 + ch) * 4096 + w];
    s[0] += bf2f(h[0]); s[1] += bf2f(h[1]); s[2] += bf2f(h[2]); s[3] += bf2f(h[3]);
  }
  ((f32x4*)T)[f] = s;
  ushort4v h; h[0]=f2bf(s[0]); h[1]=f2bf(s[1]); h[2]=f2bf(s[2]); h[3]=f2bf(s[3]);
  ((ushort4v*)Tbf)[f] = h;
}

// ---------------- NT bf16 GEMM, M=512, Nn=1024, K=1024, 32x64 tiles ----------------
template<int RELU, int HAS_BIAS, int HAS_RES, int STORE_F32, int STORE_BF16>
__global__ __launch_bounds__(256) void gemm32x64(
    const unsigned short* __restrict__ A, const unsigned short* __restrict__ Bm,
    const float* __restrict__ bias, const float* __restrict__ res,
    float* __restrict__ outF, unsigned short* __restrict__ outB)
{
  const int K = 1024;
  __shared__ __align__(16) char sh[12288];   // As 4KB | Bs 8KB, XOR-swizzled rows of 128B
  char* Asp = sh;
  char* Bsp = sh + 4096;
  int tid = threadIdx.x, wid = tid >> 6, lane = tid & 63;
  int lr = lane & 15, hi = lane >> 4;
  int m0 = blockIdx.x * 32, n0 = blockIdx.y * 64;
  int arow = tid >> 3, acol = (tid & 7) * 8;   // A stage: 32x64
  int brow = tid >> 2, bcol = (tid & 3) * 16;  // B stage: 64x64
  const unsigned short* Ap = A + (size_t)(m0 + arow) * K + acol;
  const unsigned short* Bp = Bm + (size_t)(n0 + brow) * K + bcol;
  int aw  = arow * 128 + (((acol * 2) ^ ((arow & 7) << 4)));
  int bw0 = brow * 128 + (((bcol * 2) ^ ((brow & 7) << 4)));
  int bw1 = brow * 128 + ((((bcol * 2) + 16) ^ ((brow & 7) << 4)));
  short8 aR[2]; short8 bR[2][2];
  aR[0]    = *(const short8*)(Ap);
  bR[0][0] = *(const short8*)(Bp);
  bR[0][1] = *(const short8*)(Bp + 8);
  aR[1]    = *(const short8*)(Ap + 64);
  bR[1][0] = *(const short8*)(Bp + 64);
  bR[1][1] = *(const short8*)(Bp + 72);
  f32x4 acc[2];
  acc[0] = (f32x4)0.f; acc[1] = (f32x4)0.f;
  int wm = (wid >> 1) * 16, wn = (wid & 1) * 32;
  int arb = (wm + lr) * 128, arx = ((wm + lr) & 7) << 4;
  for (int s = 0; s < 16; ++s) {
    __syncthreads();
    *(short8*)(Asp + aw)  = aR[s & 1];
    *(short8*)(Bsp + bw0) = bR[s & 1][0];
    *(short8*)(Bsp + bw1) = bR[s & 1][1];
    __syncthreads();
    if (s + 2 < 16) {
      int k0 = (s + 2) * 64;
      aR[s & 1]    = *(const short8*)(Ap + k0);
      bR[s & 1][0] = *(const short8*)(Bp + k0);
      bR[s & 1][1] = *(const short8*)(Bp + k0 + 8);
    }
#pragma unroll
    for (int kk = 0; kk < 2; ++kk) {
      short8 af = *(const short8*)(Asp + arb + (((kk * 64 + hi * 16) ^ arx)));
#pragma unroll
      for (int sn = 0; sn < 2; ++sn) {
        int br = wn + sn * 16 + lr;
        short8 bf = *(const short8*)(Bsp + br * 128 + (((kk * 64 + hi * 16) ^ ((br & 7) << 4))));
        acc[sn] = __builtin_amdgcn_mfma_f32_16x16x32_bf16(af, bf, acc[sn], 0, 0, 0);
      }
    }
  }
  int row0 = m0 + wm + hi * 4;
#pragma unroll
  for (int sn = 0; sn < 2; ++sn) {
    int col = n0 + wn + sn * 16 + lr;
    float bv_ = HAS_BIAS ? bias[col] : 0.f;
#pragma unroll
    for (int rr = 0; rr < 4; ++rr) {
      float x = acc[sn][rr] + bv_;
      if (RELU) x = fmaxf(x, 0.f);
      size_t idx = (size_t)(row0 + rr) * 1024 + col;
      if (HAS_RES) x += res[idx];
      if (STORE_F32) outF[idx] = x;
      if (STORE_BF16) outB[idx] = f2bf(x);
    }
  }
}

// ---------------- token self-attn: scores + softmax + T_dash (c-split 8) ----------------
__global__ __launch_bounds__(256) void scores_tdash(
    const float* __restrict__ kq, const float* __restrict__ T,
    float* __restrict__ Tdash, unsigned short* __restrict__ Tdbf)
{
  int cs = blockIdx.x, b = blockIdx.y;
  int c0 = cs * 128;
  __shared__ float Ts[16][128];
  int tid = threadIdx.x, lane = tid & 63;
#pragma unroll
  for (int i = 0; i < 2; ++i) {
    int fi = tid + 256 * i;            // f4 over 512
    int rrow = fi >> 5, c4 = (fi & 31) * 4;
    *(f32x4*)&Ts[rrow][c4] = *(const f32x4*)&T[((size_t)b * 16 + rrow) * 1024 + c0 + c4];
  }
  __syncthreads();
  int l = tid >> 4, m = tid & 15;
  const float* krow = kq + ((size_t)b * 16 + l) * 1024;
  const float* qrow = kq + ((size_t)b * 16 + m) * 1024 + 512;
  float s = 0.f;
#pragma unroll 8
  for (int d = 0; d < 512; d += 4) {
    f32x4 kv = *(const f32x4*)(krow + d);
    f32x4 qv = *(const f32x4*)(qrow + d);
    s += kv[0]*qv[0] + kv[1]*qv[1] + kv[2]*qv[2] + kv[3]*qv[3];
  }
  float mx = s;
  mx = fmaxf(mx, __shfl_xor(mx, 1)); mx = fmaxf(mx, __shfl_xor(mx, 2));
  mx = fmaxf(mx, __shfl_xor(mx, 4)); mx = fmaxf(mx, __shfl_xor(mx, 8));
  float e = __expf(s - mx);
  float sum = e;
  sum += __shfl_xor(sum, 1); sum += __shfl_xor(sum, 2);
  sum += __shfl_xor(sum, 4); sum += __shfl_xor(sum, 8);
  float pv = e / sum;
  float pl[16];
#pragma unroll
  for (int i = 0; i < 16; ++i) pl[i] = __shfl(pv, (lane & 48) + i);
  float* od = Tdash + ((size_t)b * 16 + l) * 1024 + c0;
  unsigned short* ob = Tdbf + ((size_t)b * 16 + l) * 1024 + c0;
#pragma unroll
  for (int h = 0; h < 2; ++h) {
    int c = m * 8 + h * 4;
    f32x4 o = *(const f32x4*)&Ts[l][c];
#pragma unroll
    for (int mm = 0; mm < 16; ++mm) {
      f32x4 tv = *(const f32x4*)&Ts[mm][c];
      o += pl[mm] * tv;
    }
    *(f32x4*)(od + c) = o;
    ushort4v hh; hh[0]=f2bf(o[0]); hh[1]=f2bf(o[1]); hh[2]=f2bf(o[2]); hh[3]=f2bf(o[3]);
    *(ushort4v*)(ob + c) = hh;
  }
}

// ---------------- r[b,l] = q_b . Tk[b,l,:] ----------------
__global__ __launch_bounds__(256) void r_kernel(
    const unsigned short* __restrict__ Tkbf, const float* __restrict__ qb,
    float* __restrict__ r)
{
  int row = blockIdx.x * 4 + (threadIdx.x >> 6);
  int lane = threadIdx.x & 63;
  const unsigned short* p = Tkbf + (size_t)row * CC;
  float s = 0.f;
#pragma unroll
  for (int h = 0; h < 2; ++h) {
    int d0 = lane * 8 + h * 512;
    short8 v = *(const short8*)&p[d0];
#pragma unroll
    for (int jj = 0; jj < 8; ++jj)
      s += bf2f((unsigned short)v[jj]) * qb[d0 + jj];
  }
#pragma unroll
  for (int msk = 32; msk >= 1; msk >>= 1) s += __shfl_xor(s, msk);
  if (lane == 0) r[row] = s;
}

// ---------------- fused sim + out: P in LDS, X_out = X + P @ T_out ----------------
__global__ __launch_bounds__(256) void sim_out_kernel(
    const float* __restrict__ X, const unsigned short* __restrict__ Gt,
    const float* __restrict__ rbias, const float* __restrict__ Tout,
    float* __restrict__ Xout)
{
  __shared__ __align__(16) char sp[16384];
  __shared__ float Ps[64][16];
  int tid = threadIdx.x, wid = tid >> 6, lane = tid & 63;
  int lr = lane & 15, hi = lane >> 4;
  int pix0 = blockIdx.x * 64 + blockIdx.y * 1024;
  int b = blockIdx.y;
  int row = tid >> 2, seg = tid & 3;
  const float* xr = X + (size_t)(pix0 + row) * 1024 + seg * 32;
  const unsigned short* Wb = Gt + (size_t)b * 16 * 1024 + (size_t)lr * 1024 + hi * 8;
  int wbyte[4];
#pragma unroll
  for (int u = 0; u < 4; ++u)
    wbyte[u] = row * 256 + (((seg * 64 + u * 16) ^ ((row & 7) << 4)));
  int arow = wid * 16 + lr;
  int rbyte = arow * 256;
  int rx = (arow & 7) << 4;
  f32x4 acc = (f32x4)0.f;
  for (int k0 = 0; k0 < 1024; k0 += 128) {
    f32x4 v[8];
#pragma unroll
    for (int i = 0; i < 8; ++i) v[i] = *(const f32x4*)(xr + k0 + i * 4);
    __syncthreads();
#pragma unroll
    for (int u = 0; u < 4; ++u) {
      short8 pk;
      pk[0] = (short)f2bf(v[2*u][0]);   pk[1] = (short)f2bf(v[2*u][1]);
      pk[2] = (short)f2bf(v[2*u][2]);   pk[3] = (short)f2bf(v[2*u][3]);
      pk[4] = (short)f2bf(v[2*u+1][0]); pk[5] = (short)f2bf(v[2*u+1][1]);
      pk[6] = (short)f2bf(v[2*u+1][2]); pk[7] = (short)f2bf(v[2*u+1][3]);
      *(short8*)(sp + wbyte[u]) = pk;
    }
    __syncthreads();
#pragma unroll
    for (int kk = 0; kk < 4; ++kk) {
      short8 af = *(const short8*)(sp + rbyte + (((kk * 64 + hi * 16) ^ rx)));
      short8 bf = *(const short8*)(Wb + k0 + kk * 32);
      acc = __builtin_amdgcn_mfma_f32_16x16x32_bf16(af, bf, acc, 0, 0, 0);
    }
  }
  // in-register softmax over l (16-lane groups), P -> LDS
  float bv = rbias[b * 16 + lr];
  int prow = wid * 16 + hi * 4;
#pragma unroll
  for (int rr = 0; rr < 4; ++rr) {
    float vv = acc[rr] + bv;
    float mx = vv;
    mx = fmaxf(mx, __shfl_xor(mx, 1)); mx = fmaxf(mx, __shfl_xor(mx, 2));
    mx = fmaxf(mx, __shfl_xor(mx, 4)); mx = fmaxf(mx, __shfl_xor(mx, 8));
    float e = __expf(vv - mx);
    float ss = e;
    ss += __shfl_xor(ss, 1); ss += __shfl_xor(ss, 2);
    ss += __shfl_xor(ss, 4); ss += __shfl_xor(ss, 8);
    Ps[prow + rr][lr] = e / ss;
  }
  __syncthreads();
  // phase 2: X_out = X + P @ T_out, T_out column-slice in registers
  int c4 = tid * 4;
  f32x4 tsr[16];
#pragma unroll
  for (int l = 0; l < 16; ++l)
    tsr[l] = *(const f32x4*)&Tout[((size_t)b * 16 + l) * 1024 + c4];
  const float* xp = X + (size_t)pix0 * 1024 + c4;
  float* op = Xout + (size_t)pix0 * 1024 + c4;
#pragma unroll 2
  for (int n = 0; n < 64; ++n) {
    f32x4 xv = *(const f32x4*)(xp + (size_t)n * 1024);
    const f32x4* pr = (const f32x4*)&Ps[n][0];
    f32x4 p0 = pr[0], p1 = pr[1], p2 = pr[2], p3 = pr[3];
    f32x4 o = xv;
    o += p0[0]*tsr[0];  o += p0[1]*tsr[1];  o += p0[2]*tsr[2];  o += p0[3]*tsr[3];
    o += p1[0]*tsr[4];  o += p1[1]*tsr[5];  o += p1[2]*tsr[6];  o += p1[3]*tsr[7];
    o += p2[0]*tsr[8];  o += p2[1]*tsr[9];  o += p2[2]*tsr[10]; o += p2[3]*tsr[11];
    o += p3[0]*tsr[12]; o += p3[1]*tsr[13]; o += p3[2]*tsr[14]; o += p3[3]*tsr[15];
    *(f32x4*)(op + (size_t)n * 1024) = o;
  }
}

extern "C" void kernel_launch(void* const* d_in, const int* in_sizes, int n_in,
                              void* d_out, int out_size, void* d_ws, size_t ws_size,
                              hipStream_t stream)
{
  const float* X      = (const float*)d_in[0];
  const float* tokW   = (const float*)d_in[2];
  const float* tokB   = (const float*)d_in[3];
  const float* keyW   = (const float*)d_in[4];
  const float* keyB   = (const float*)d_in[5];
  const float* queryW = (const float*)d_in[6];
  const float* queryB = (const float*)d_in[7];
  const float* f1W    = (const float*)d_in[8];
  const float* f1B    = (const float*)d_in[9];
  const float* f2W    = (const float*)d_in[10];
  const float* f2B    = (const float*)d_in[11];
  const float* qW     = (const float*)d_in[12];
  const float* qB     = (const float*)d_in[13];
  const float* kW     = (const float*)d_in[14];
  const float* kB     = (const float*)d_in[15];

  float* Xout = (float*)d_out;
  float* Tout = (float*)d_out + (size_t)BB * NN * CC;

  char* ws = (char*)d_ws;
  size_t off = 0;
  auto alloc_f = [&](size_t n) { float* pp = (float*)(ws + off); off += n * 4; return pp; };
  float* attn   = alloc_f(524288);    // [B*L][N] logits -> softmaxed in place
  float* Tbuf   = alloc_f(524288);    // [B*L][C]
  float* kqbuf  = alloc_f(524288);    // [B*L][1024] (k | q)
  float* Tdash  = alloc_f(524288);
  float* rbuf   = alloc_f(1024);
  float* biaskq = alloc_f(1024);
  auto alloc_h = [&](size_t n) { unsigned short* pp = (unsigned short*)(ws + off); off += n * 2; return pp; };
  unsigned short* TpartBf = alloc_h(4194304);   // [B][8][L][C] bf16
  unsigned short* Tbf    = alloc_h(524288);
  unsigned short* Tdbf   = alloc_h(524288);
  unsigned short* Hbf    = alloc_h(524288);
  unsigned short* Toutbf = alloc_h(524288);
  unsigned short* Tkbf   = alloc_h(524288);
  unsigned short* Gtbf   = alloc_h(524288);     // [B*L][C] bf16
  unsigned short* WkqT   = alloc_h(1048576);
  unsigned short* f1WT   = alloc_h(1048576);
  unsigned short* f2WT   = alloc_h(1048576);
  unsigned short* kWT    = alloc_h(1048576);
  unsigned short* qWbf   = alloc_h(1048576);
  unsigned short* tokWT  = alloc_h(16384);
  (void)ws_size; (void)in_sizes; (void)n_in; (void)out_size;

  wprep<<<dim3(32, 32, 6), dim3(32, 8), 0, stream>>>(keyW, queryW, f1W, f2W, kW, qW,
                                                     tokW, keyB, queryB,
                                                     WkqT, f1WT, f2WT, kWT, qWbf, tokWT, biaskq);
  proj_mfma<<<dim3(512), 256, 0, stream>>>(X, tokWT, tokB, attn);
  softmax_n<<<512, 256, 0, stream>>>(attn);
  tpart_kernel<<<dim3(8, 32), 256, 0, stream>>>(X, attn, TpartBf);
  treduce<<<512, 256, 0, stream>>>(TpartBf, Tbuf, Tbf);
  gemm32x64<0,1,0,1,0><<<dim3(16, 16), 256, 0, stream>>>(Tbf, WkqT, biaskq, nullptr, kqbuf, nullptr);
  scores_tdash<<<dim3(8, 32), 256, 0, stream>>>(kqbuf, Tbuf, Tdash, Tdbf);
  gemm32x64<1,1,0,0,1><<<dim3(16, 16), 256, 0, stream>>>(Tdbf, f1WT, f1B, nullptr, nullptr, Hbf);
  gemm32x64<0,1,1,1,1><<<dim3(16, 16), 256, 0, stream>>>(Hbf, f2WT, f2B, Tdash, Tout, Toutbf);
  gemm32x64<0,1,0,0,1><<<dim3(16, 16), 256, 0, stream>>>(Toutbf, kWT, kB, nullptr, nullptr, Tkbf);
  r_kernel<<<128, 256, 0, stream>>>(Tkbf, qB, rbuf);
  gemm32x64<0,0,0,0,1><<<dim3(16, 16), 256, 0, stream>>>(Tkbf, qWbf, nullptr, nullptr, nullptr, Gtbf);
  sim_out_kernel<<<dim3(16, 32), 256, 0, stream>>>(X, Gtbf, rbuf, Tout, Xout);
}